// Round 1
// baseline (735.972 us; speedup 1.0000x reference)
//
#include <hip/hip_runtime.h>
#include <math.h>

#define Bn 256
#define Cc 3
#define Hh 256
#define Ww 256
#define HW (Hh*Ww)        // 65536
#define CHW (Cc*HW)       // 196608

// ws layout (floats): [0..255] per-image sums, then per-image params stride 10
#define P_BASE 256
#define P_STRIDE 10
// param indices: 0 cth, 1 sth, 2 flip, 3 startY, 4 scaleY, 5 startX, 6 scaleX,
//                7 delta, 8 mag1, 9 mag2

#define TS 16             // output tile
#define RDIM 27           // staged source region (rotated bbox), fixed
#define S2 17             // stage-2 patch dim
#define S2S 18            // stage-2 LDS stride (pad)

__global__ void setup_params(const float* __restrict__ th, const float* __restrict__ fl,
                             const float* __restrict__ sz, const float* __restrict__ sh,
                             const float* __restrict__ de, const float* __restrict__ m1,
                             const float* __restrict__ m2, float* __restrict__ ws) {
    int b = threadIdx.x;   // one thread per image, 256 threads
    ws[b] = 0.0f;          // zero the sum slot (ws poisoned 0xAA each launch)
    float* p = ws + P_BASE + b * P_STRIDE;
    float theta = (th[b] * 2.0f - 1.0f) * 3.14159265358979323846f;  // ROT_DEG=180 -> pi
    p[0] = cosf(theta);
    p[1] = sinf(theta);
    p[2] = (fl[b] > 0.5f) ? 1.0f : 0.0f;
    #pragma unroll
    for (int d = 0; d < 2; d++) {   // d=0 -> y (rows), d=1 -> x (cols)
        float s     = rintf(256.0f * (sz[b*2 + d] * 0.25f + 1.0f) - 0.5f); // jnp.round = rint
        float ms    = s - 256.0f;                 // max_shift
        float sr    = ms - 1e-5f;                 // shift_range
        float shf   = rintf(sh[b*2 + d] * sr - sr * 0.5f);
        float start = floorf(ms * 0.5f) + shf;
        p[3 + 2*d]  = start;
        p[4 + 2*d]  = 255.0f / (s - 1.0f);        // scale
    }
    p[7] = (de[b] * 2.0f - 1.0f) * 0.3f;          // delta
    p[8] = (m1[b] * 2.0f - 1.0f) * 0.3f + 1.0f;   // mag1
    p[9] = (m2[b] * 2.0f - 1.0f) * 0.3f + 1.0f;   // mag2
}

__global__ __launch_bounds__(256)
void augment_main(const float* __restrict__ img, const float* __restrict__ wsp,
                  float* __restrict__ out, float* __restrict__ sums) {
    __shared__ float L1[Cc * RDIM * RDIM];   // rotated-source staging (8748 B)
    __shared__ float L2[Cc * S2 * S2S];      // stage-2 patch (3672 B)
    __shared__ float wred[4];

    const int tid   = threadIdx.x;
    const int b     = blockIdx.z;
    const int tileY = blockIdx.y * TS;
    const int tileX = blockIdx.x * TS;

    const float* p = wsp + P_BASE + b * P_STRIDE;
    const float cth = p[0], sth = p[1];
    const bool  flip = p[2] > 0.5f;
    const float startY = p[3], scaleY = p[4];
    const float startX = p[5], scaleX = p[6];
    const float delta = p[7], mag1 = p[8];

    // ---- stage-2 patch origin (crop-resize source rows/cols for this tile) ----
    float sy0 = fminf(fmaxf((startY + (float)tileY) * scaleY, 0.0f), 255.0f);
    float sx0 = fminf(fmaxf((startX + (float)tileX) * scaleX, 0.0f), 255.0f);
    const int rY = (int)floorf(sy0);
    const int rX = (int)floorf(sx0);

    // ---- rotated bounding box of the stage-1 coords needed for the patch ----
    const int Ymax = min(rY + TS, 255);
    const int Xt1  = min(rX + TS, 255);
    const int Xf0  = flip ? 255 - Xt1 : rX;
    const int Xf1  = flip ? 255 - rX  : Xt1;
    const float xg0 = ((float)(2*Xf0 + 1)) * (1.0f/256.0f) - 1.0f;
    const float xg1 = ((float)(2*Xf1 + 1)) * (1.0f/256.0f) - 1.0f;
    const float yg0 = ((float)(2*rY  + 1)) * (1.0f/256.0f) - 1.0f;
    const float yg1 = ((float)(2*Ymax + 1)) * (1.0f/256.0f) - 1.0f;

    float ixmin = 1e30f, ixmax = -1e30f, iymin = 1e30f, iymax = -1e30f;
    #pragma unroll
    for (int cy = 0; cy < 2; cy++) {
        #pragma unroll
        for (int cx = 0; cx < 2; cx++) {
            float xg = cx ? xg1 : xg0;
            float yg = cy ? yg1 : yg0;
            float xp = cth * xg - sth * yg;
            float yp = sth * xg + cth * yg;
            float ix = ((xp + 1.0f) * 256.0f - 1.0f) * 0.5f;
            float iy = ((yp + 1.0f) * 256.0f - 1.0f) * 0.5f;
            ixmin = fminf(ixmin, ix); ixmax = fmaxf(ixmax, ix);
            iymin = fminf(iymin, iy); iymax = fmaxf(iymax, iy);
        }
    }
    const int bx0 = (int)floorf(ixmin) - 1;   // -1/+2 margin: width <= 27 guaranteed
    const int by0 = (int)floorf(iymin) - 1;
    const int gx0 = min(max(bx0, 0), 255);
    const int gy0 = min(max(by0, 0), 255);

    // ---- Phase A: coalesced load of the 27x27x3 source region into LDS ----
    const float* imgb = img + (size_t)b * CHW;
    for (int i = tid; i < Cc * RDIM * RDIM; i += 256) {
        int c  = i / (RDIM * RDIM);
        int rm = i - c * (RDIM * RDIM);
        int r  = rm / RDIM;
        int q  = rm - r * RDIM;
        int ry = min(gy0 + r, 255);
        int rx = min(gx0 + q, 255);
        L1[i] = imgb[c * HW + ry * Ww + rx];
    }
    __syncthreads();

    // ---- Phase B: rotate (+flip remap) -> stage-2 patch in LDS ----
    for (int pI = tid; pI < S2 * S2; pI += 256) {
        int lY = pI / S2;
        int lX = pI - lY * S2;
        int Yc = min(rY + lY, 255);
        int Xc = min(rX + lX, 255);
        int Xf = flip ? 255 - Xc : Xc;
        float xg = ((float)(2*Xf + 1)) * (1.0f/256.0f) - 1.0f;
        float yg = ((float)(2*Yc + 1)) * (1.0f/256.0f) - 1.0f;
        float xp = cth * xg - sth * yg;
        float yp = sth * xg + cth * yg;
        float ixf = ((xp + 1.0f) * 256.0f - 1.0f) * 0.5f;
        float iyf = ((yp + 1.0f) * 256.0f - 1.0f) * 0.5f;
        float rx0f = floorf(ixf), ry0f = floorf(iyf);
        float fx = ixf - rx0f,  fy = iyf - ry0f;
        // zeros-pad validity folded into weights (float-coord test, as reference)
        float wx0 = (rx0f >= 0.0f        && rx0f <= 255.0f)        ? (1.0f - fx) : 0.0f;
        float wx1 = (rx0f + 1.0f >= 0.0f && rx0f + 1.0f <= 255.0f) ? fx          : 0.0f;
        float wy0 = (ry0f >= 0.0f        && ry0f <= 255.0f)        ? (1.0f - fy) : 0.0f;
        float wy1 = (ry0f + 1.0f >= 0.0f && ry0f + 1.0f <= 255.0f) ? fy          : 0.0f;
        int x0i = (int)rx0f, y0i = (int)ry0f;
        int ax0 = min(max(min(max(x0i,     0), 255) - gx0, 0), RDIM - 1);
        int ax1 = min(max(min(max(x0i + 1, 0), 255) - gx0, 0), RDIM - 1);
        int ay0 = min(max(min(max(y0i,     0), 255) - gy0, 0), RDIM - 1);
        int ay1 = min(max(min(max(y0i + 1, 0), 255) - gy0, 0), RDIM - 1);
        float w00 = wy0 * wx0, w01 = wy0 * wx1, w10 = wy1 * wx0, w11 = wy1 * wx1;
        int i00 = ay0 * RDIM + ax0, i01 = ay0 * RDIM + ax1;
        int i10 = ay1 * RDIM + ax0, i11 = ay1 * RDIM + ax1;
        #pragma unroll
        for (int c = 0; c < Cc; c++) {
            const float* Lc = L1 + c * (RDIM * RDIM);
            float v = w00 * Lc[i00] + w01 * Lc[i01] + w10 * Lc[i10] + w11 * Lc[i11];
            L2[c * (S2 * S2S) + lY * S2S + lX] = v;
        }
    }
    __syncthreads();

    // ---- Phase C: crop-resize bilinear (clamp mode) + color ops + sum ----
    const int py = tid >> 4, px = tid & 15;
    const int y = tileY + py, x = tileX + px;
    float sy = fminf(fmaxf((startY + (float)y) * scaleY, 0.0f), 255.0f);
    float sx = fminf(fmaxf((startX + (float)x) * scaleX, 0.0f), 255.0f);
    float y0f = floorf(sy), x0f = floorf(sx);
    float fy = sy - y0f, fx = sx - x0f;
    int y0 = (int)y0f, x0 = (int)x0f;
    int y1 = min(y0 + 1, 255), x1 = min(x0 + 1, 255);
    int ly0 = min(max(y0 - rY, 0), S2 - 1), ly1 = min(max(y1 - rY, 0), S2 - 1);
    int lx0 = min(max(x0 - rX, 0), S2 - 1), lx1 = min(max(x1 - rX, 0), S2 - 1);
    float w00 = (1.0f - fy) * (1.0f - fx), w01 = (1.0f - fy) * fx;
    float w10 = fy * (1.0f - fx),          w11 = fy * fx;

    float x4[3];
    #pragma unroll
    for (int c = 0; c < Cc; c++) {
        const float* Lc = L2 + c * (S2 * S2S);
        float v = w00 * Lc[ly0*S2S + lx0] + w01 * Lc[ly0*S2S + lx1]
                + w10 * Lc[ly1*S2S + lx0] + w11 * Lc[ly1*S2S + lx1];
        x4[c] = v + delta;
    }
    float mc = (x4[0] + x4[1] + x4[2]) * (1.0f/3.0f);
    float s5 = 0.0f;
    float* outb = out + (size_t)b * CHW + y * Ww + x;
    #pragma unroll
    for (int c = 0; c < Cc; c++) {
        float v5 = (x4[c] - mc) * mag1 + mc;
        outb[c * HW] = v5;
        s5 += v5;
    }
    // block reduction of sum(x5)
    #pragma unroll
    for (int off = 32; off > 0; off >>= 1) s5 += __shfl_down(s5, off, 64);
    int lane = tid & 63, wid = tid >> 6;
    if (lane == 0) wred[wid] = s5;
    __syncthreads();
    if (tid == 0) atomicAdd(&sums[b], wred[0] + wred[1] + wred[2] + wred[3]);
}

__global__ __launch_bounds__(256)
void finalize_k(float* __restrict__ out, const float* __restrict__ wsp) {
    const int b = blockIdx.y;
    const float m    = wsp[b] * (1.0f / (float)CHW);
    const float mag2 = wsp[P_BASE + b * P_STRIDE + 9];
    float4* ob = (float4*)(out + (size_t)b * CHW);
    int idx = blockIdx.x * 256 + threadIdx.x;
    float4 v = ob[idx];
    v.x = (v.x - m) * mag2 + m;
    v.y = (v.y - m) * mag2 + m;
    v.z = (v.z - m) * mag2 + m;
    v.w = (v.w - m) * mag2 + m;
    ob[idx] = v;
}

extern "C" void kernel_launch(void* const* d_in, const int* in_sizes, int n_in,
                              void* d_out, int out_size, void* d_ws, size_t ws_size,
                              hipStream_t stream) {
    const float* img = (const float*)d_in[0];
    const float* th  = (const float*)d_in[1];
    const float* fl  = (const float*)d_in[2];
    const float* sz  = (const float*)d_in[3];
    const float* sh  = (const float*)d_in[4];
    const float* de  = (const float*)d_in[5];
    const float* m1  = (const float*)d_in[6];
    const float* m2  = (const float*)d_in[7];
    float* out = (float*)d_out;
    float* ws  = (float*)d_ws;

    hipLaunchKernelGGL(setup_params, dim3(1), dim3(256), 0, stream,
                       th, fl, sz, sh, de, m1, m2, ws);
    hipLaunchKernelGGL(augment_main, dim3(Ww/TS, Hh/TS, Bn), dim3(256), 0, stream,
                       img, ws, out, ws);
    hipLaunchKernelGGL(finalize_k, dim3(CHW/4/256, Bn), dim3(256), 0, stream,
                       out, ws);
}

// Round 2
// 699.168 us; speedup vs baseline: 1.0526x; 1.0526x over previous
//
#include <hip/hip_runtime.h>
#include <math.h>

#define Bn 256
#define Cc 3
#define Hh 256
#define Ww 256
#define HW (Hh*Ww)        // 65536
#define CHW (Cc*HW)       // 196608

// ws layout (floats): [0..255] per-image sums, then per-image params stride 10
#define P_BASE 256
#define P_STRIDE 10
// param indices: 0 cth, 1 sth, 2 flip, 3 startY, 4 scaleY, 5 startX, 6 scaleX,
//                7 delta, 8 mag1, 9 mag2

#define TS 16             // output tile
#define RDIM 29           // staged source region (rotated bbox of 18x18 patch), odd stride
#define PLANE1 (RDIM*RDIM)        // 841
#define N1 (Cc*PLANE1)            // 2523
#define S2 18             // stage-2 patch dim (17 + 1 fp-edge guard row/col)
#define S2S 20            // stage-2 LDS row stride
#define PLANE2 (S2*S2S)           // 360

__global__ void setup_params(const float* __restrict__ th, const float* __restrict__ fl,
                             const float* __restrict__ sz, const float* __restrict__ sh,
                             const float* __restrict__ de, const float* __restrict__ m1,
                             const float* __restrict__ m2, float* __restrict__ ws) {
    int b = threadIdx.x;   // one thread per image
    ws[b] = 0.0f;          // zero the sum slot (ws poisoned 0xAA each launch)
    float* p = ws + P_BASE + b * P_STRIDE;
    float theta = (th[b] * 2.0f - 1.0f) * 3.14159265358979323846f;  // ROT_DEG=180 -> pi
    p[0] = cosf(theta);
    p[1] = sinf(theta);
    p[2] = (fl[b] > 0.5f) ? 1.0f : 0.0f;
    #pragma unroll
    for (int d = 0; d < 2; d++) {   // d=0 -> y (rows), d=1 -> x (cols)
        float s     = rintf(256.0f * (sz[b*2 + d] * 0.25f + 1.0f) - 0.5f); // jnp.round = rint
        float ms    = s - 256.0f;
        float sr    = ms - 1e-5f;
        float shf   = rintf(sh[b*2 + d] * sr - sr * 0.5f);
        float start = floorf(ms * 0.5f) + shf;
        p[3 + 2*d]  = start;
        p[4 + 2*d]  = 255.0f / (s - 1.0f);
    }
    p[7] = (de[b] * 2.0f - 1.0f) * 0.3f;
    p[8] = (m1[b] * 2.0f - 1.0f) * 0.3f + 1.0f;
    p[9] = (m2[b] * 2.0f - 1.0f) * 0.3f + 1.0f;
}

__global__ __launch_bounds__(256)
void augment_main(const float* __restrict__ img, const float* __restrict__ wsp,
                  float* __restrict__ out, float* __restrict__ sums) {
    __shared__ float L1[N1];        // rotated-source staging, UNclamped origin (10092 B)
    __shared__ float L2[Cc*PLANE2]; // stage-2 patch 18x18, stride 20 (4320 B)
    __shared__ float wred[4];

    const int tid   = threadIdx.x;
    const int b     = blockIdx.z;
    const int tileY = blockIdx.y * TS;
    const int tileX = blockIdx.x * TS;

    const float* p = wsp + P_BASE + b * P_STRIDE;
    const float cth = p[0], sth = p[1];
    const bool  flip = p[2] > 0.5f;
    const float startY = p[3], scaleY = p[4];
    const float startX = p[5], scaleX = p[6];
    const float delta = p[7], mag1 = p[8];

    // ---- stage-2 patch origin (crop-resize source rows/cols for this tile) ----
    float sy0 = fminf(fmaxf((startY + (float)tileY) * scaleY, 0.0f), 255.0f);
    float sx0 = fminf(fmaxf((startX + (float)tileX) * scaleX, 0.0f), 255.0f);
    const int rY = (int)floorf(sy0);
    const int rX = (int)floorf(sx0);

    // ---- rotated bbox of the stage-1 coords needed for the 18x18 patch ----
    const int Ymax = min(rY + S2 - 1, 255);
    const int Xt1  = min(rX + S2 - 1, 255);
    const int Xf0  = flip ? 255 - Xt1 : rX;
    const int Xf1  = flip ? 255 - rX  : Xt1;
    // xg = (2X+1)/256 - 1 = X*(1/128) + (1/256 - 1), exact in fp32
    const float xg0 = fmaf((float)Xf0, 0.0078125f, -0.99609375f);
    const float xg1 = fmaf((float)Xf1, 0.0078125f, -0.99609375f);
    const float yg0 = fmaf((float)rY,  0.0078125f, -0.99609375f);
    const float yg1 = fmaf((float)Ymax,0.0078125f, -0.99609375f);

    float ixmin = 1e30f, iymin = 1e30f;
    #pragma unroll
    for (int cy = 0; cy < 2; cy++) {
        #pragma unroll
        for (int cx = 0; cx < 2; cx++) {
            float xg = cx ? xg1 : xg0;
            float yg = cy ? yg1 : yg0;
            float xp = cth * xg - sth * yg;
            float yp = sth * xg + cth * yg;
            ixmin = fminf(ixmin, fmaf(xp, 128.0f, 127.5f));
            iymin = fminf(iymin, fmaf(yp, 128.0f, 127.5f));
        }
    }
    // UNclamped origin: indices ax=x0-bx0 are in [0,RDIM-2] by construction.
    const int bx0 = (int)floorf(ixmin) - 1;
    const int by0 = (int)floorf(iymin) - 1;

    // ---- Phase A: load 29x29x3 region into LDS, border-replicated ----
    const float* imgb = img + (size_t)b * CHW;
    #pragma unroll
    for (int k = 0; k < 10; k++) {
        int i = tid + (k << 8);
        if (i < N1) {
            int c  = i / PLANE1;
            int rm = i - c * PLANE1;
            int r  = rm / RDIM;
            int q  = rm - r * RDIM;
            int ry = min(max(by0 + r, 0), 255);
            int rx = min(max(bx0 + q, 0), 255);
            L1[i] = imgb[(c << 16) + (ry << 8) + rx];
        }
    }
    __syncthreads();

    // ---- Phase B: rotate (+flip remap) -> 18x18 stage-2 patch in LDS ----
    for (int i = tid; i < S2 * S2; i += 256) {
        int lY = i / S2;
        int lX = i - lY * S2;
        int Yc = min(rY + lY, 255);
        int Xc = min(rX + lX, 255);
        int Xf = flip ? 255 - Xc : Xc;
        float xg = fmaf((float)Xf, 0.0078125f, -0.99609375f);
        float yg = fmaf((float)Yc, 0.0078125f, -0.99609375f);
        float xp = cth * xg - sth * yg;
        float yp = sth * xg + cth * yg;
        float ixf = fmaf(xp, 128.0f, 127.5f);
        float iyf = fmaf(yp, 128.0f, 127.5f);
        float x0f = floorf(ixf), y0f = floorf(iyf);
        float fx = ixf - x0f, fy = iyf - y0f;
        // zeros-pad validity folded into weights (float-coord test, as reference)
        float wx0 = (x0f >=  0.0f && x0f <= 255.0f) ? (1.0f - fx) : 0.0f;
        float wx1 = (x0f >= -1.0f && x0f <= 254.0f) ? fx          : 0.0f;
        float wy0 = (y0f >=  0.0f && y0f <= 255.0f) ? (1.0f - fy) : 0.0f;
        float wy1 = (y0f >= -1.0f && y0f <= 254.0f) ? fy          : 0.0f;
        int ax = (int)x0f - bx0;    // in [0, RDIM-2] by construction
        int ay = (int)y0f - by0;
        int ib = ay * RDIM + ax;
        float w00 = wy0 * wx0, w01 = wy0 * wx1, w10 = wy1 * wx0, w11 = wy1 * wx1;
        int ob = lY * S2S + lX;
        #pragma unroll
        for (int c = 0; c < Cc; c++) {
            const float* Lc = L1 + c * PLANE1;
            // pairs [ib],[ib+1] and [ib+RDIM],[ib+RDIM+1] -> ds_read2_b32
            float v = w00 * Lc[ib]        + w01 * Lc[ib + 1]
                    + w10 * Lc[ib + RDIM] + w11 * Lc[ib + RDIM + 1];
            L2[c * PLANE2 + ob] = v;
        }
    }
    __syncthreads();

    // ---- Phase C: crop-resize bilinear (clamp mode) + color ops + sum ----
    const int py = tid >> 4, px = tid & 15;
    const int y = tileY + py, x = tileX + px;
    float sy = fminf(fmaxf((startY + (float)y) * scaleY, 0.0f), 255.0f);
    float sx = fminf(fmaxf((startX + (float)x) * scaleX, 0.0f), 255.0f);
    float y0f = floorf(sy), x0f = floorf(sx);
    float fy = sy - y0f, fx = sx - x0f;
    int ly = (int)y0f - rY;    // in [0,16]; +1 row exists (S2=18, clamp-replicated)
    int lx = (int)x0f - rX;
    int ib2 = ly * S2S + lx;
    float w00 = (1.0f - fy) * (1.0f - fx), w01 = (1.0f - fy) * fx;
    float w10 = fy * (1.0f - fx),          w11 = fy * fx;

    float x4[3];
    #pragma unroll
    for (int c = 0; c < Cc; c++) {
        const float* Lc = L2 + c * PLANE2;
        float v = w00 * Lc[ib2]       + w01 * Lc[ib2 + 1]
                + w10 * Lc[ib2 + S2S] + w11 * Lc[ib2 + S2S + 1];
        x4[c] = v + delta;
    }
    float mc = (x4[0] + x4[1] + x4[2]) * (1.0f/3.0f);
    float s5 = 0.0f;
    float* outb = out + (size_t)b * CHW + (y << 8) + x;
    #pragma unroll
    for (int c = 0; c < Cc; c++) {
        float v5 = (x4[c] - mc) * mag1 + mc;
        outb[c * HW] = v5;
        s5 += v5;
    }
    // block reduction of sum(x5)
    #pragma unroll
    for (int off = 32; off > 0; off >>= 1) s5 += __shfl_down(s5, off, 64);
    int lane = tid & 63, wid = tid >> 6;
    if (lane == 0) wred[wid] = s5;
    __syncthreads();
    if (tid == 0) atomicAdd(&sums[b], wred[0] + wred[1] + wred[2] + wred[3]);
}

__global__ __launch_bounds__(256)
void finalize_k(float* __restrict__ out, const float* __restrict__ wsp) {
    const int b = blockIdx.y;
    const float m    = wsp[b] * (1.0f / (float)CHW);
    const float mag2 = wsp[P_BASE + b * P_STRIDE + 9];
    float4* ob = (float4*)(out + (size_t)b * CHW);
    int idx = blockIdx.x * 256 + threadIdx.x;
    float4 v = ob[idx];
    v.x = (v.x - m) * mag2 + m;
    v.y = (v.y - m) * mag2 + m;
    v.z = (v.z - m) * mag2 + m;
    v.w = (v.w - m) * mag2 + m;
    ob[idx] = v;
}

extern "C" void kernel_launch(void* const* d_in, const int* in_sizes, int n_in,
                              void* d_out, int out_size, void* d_ws, size_t ws_size,
                              hipStream_t stream) {
    const float* img = (const float*)d_in[0];
    const float* th  = (const float*)d_in[1];
    const float* fl  = (const float*)d_in[2];
    const float* sz  = (const float*)d_in[3];
    const float* sh  = (const float*)d_in[4];
    const float* de  = (const float*)d_in[5];
    const float* m1  = (const float*)d_in[6];
    const float* m2  = (const float*)d_in[7];
    float* out = (float*)d_out;
    float* ws  = (float*)d_ws;

    hipLaunchKernelGGL(setup_params, dim3(1), dim3(256), 0, stream,
                       th, fl, sz, sh, de, m1, m2, ws);
    hipLaunchKernelGGL(augment_main, dim3(Ww/TS, Hh/TS, Bn), dim3(256), 0, stream,
                       img, ws, out, ws);
    hipLaunchKernelGGL(finalize_k, dim3(CHW/4/256, Bn), dim3(256), 0, stream,
                       out, ws);
}